// Round 1
// baseline (71.851 us; speedup 1.0000x reference)
//
#include <hip/hip_runtime.h>
#include <math.h>

#define BLOCK 256
#define CHUNK 64

#define PI_F      3.14159265358979323846f
#define TAU_F     6.2831853071795864769f
#define INV_TAU_F 0.15915494309189533577f
// phi^2 = 2.618033988749895, cutoff is dist <= phi^2  <=>  r2 <= phi^4
#define PHI4_F    6.854101966249685f

// Per-point precompute: A[i] = {x, y, ell, theta} with x = e^ell * cos(theta), y = e^ell * sin(theta)
__global__ void precompute_kernel(const float* __restrict__ ell,
                                  const float* __restrict__ theta,
                                  float4* __restrict__ A, int n) {
    int i = blockIdx.x * blockDim.x + threadIdx.x;
    if (i < n) {
        float e = ell[i];
        float th = theta[i];
        float lam = expf(e);
        float sn, cs;
        sincosf(th, &sn, &cs);
        A[i] = make_float4(lam * cs, lam * sn, e, th);
    }
}

// All-pairs repulsion. Thread t of block (bx, by) owns i = bx*BLOCK + t and
// accumulates over j in [by*CHUNK, by*CHUNK+CHUNK). j-data is wave-uniform ->
// scalar loads. Two atomicAdds per thread into out[0:N] (F_ell) / out[N:2N] (F_theta).
__global__ __launch_bounds__(BLOCK) void repulse_kernel(
        const float4* __restrict__ A,
        const float* __restrict__ s,
        const unsigned char* __restrict__ frozen,
        float* __restrict__ out, int n) {
    int i = blockIdx.x * BLOCK + threadIdx.x;
    if (i >= n) return;
    int j0 = blockIdx.y * CHUNK;

    float4 a = A[i];
    float si = s[i];
    float xi = a.x, yi = a.y, eli = a.z;
    float api = PI_F - a.w;   // t = theta_j + (pi - theta_i)

    float Fe = 0.0f, Ft = 0.0f;

    int jend = j0 + CHUNK;
    if (jend > n) jend = n;

#pragma unroll 8
    for (int j = j0; j < jend; ++j) {
        float4 b = A[j];              // uniform address -> s_load
        float sj = s[j];
        float dx = b.x - xi;
        float dy = b.y - yi;
        float r2 = fmaf(dx, dx, dy * dy);
        float f = si * sj * rsqrtf(fmaxf(r2, 1e-30f));   // s_i*s_j/dist
        bool ok = (r2 <= PHI4_F) && (j != i);
        f = ok ? f : 0.0f;
        // d_theta = mod(theta_j - theta_i + pi, tau) - pi
        float t = b.w + api;
        float dth = fmaf(-floorf(t * INV_TAU_F), TAU_F, t) - PI_F;
        Fe = fmaf(f, b.z - eli, Fe);  // force * d_ell
        Ft = fmaf(f, dth, Ft);        // force * d_theta
    }

    if (frozen[i]) { Fe = 0.0f; Ft = 0.0f; }
    atomicAdd(&out[i], Fe);
    atomicAdd(&out[n + i], Ft);
}

extern "C" void kernel_launch(void* const* d_in, const int* in_sizes, int n_in,
                              void* d_out, int out_size, void* d_ws, size_t ws_size,
                              hipStream_t stream) {
    const float* ell   = (const float*)d_in[0];
    const float* theta = (const float*)d_in[1];
    const float* s     = (const float*)d_in[2];
    const unsigned char* frozen = (const unsigned char*)d_in[3];
    float* out = (float*)d_out;
    int n = in_sizes[0];

    float4* A = (float4*)d_ws;

    // out is re-poisoned to 0xAA before every timed call -> zero it (capturable)
    hipMemsetAsync(d_out, 0, (size_t)out_size * sizeof(float), stream);

    int pre_blocks = (n + BLOCK - 1) / BLOCK;
    precompute_kernel<<<pre_blocks, BLOCK, 0, stream>>>(ell, theta, A, n);

    dim3 grid((n + BLOCK - 1) / BLOCK, (n + CHUNK - 1) / CHUNK);
    repulse_kernel<<<grid, BLOCK, 0, stream>>>(A, s, frozen, out, n);
}

// Round 2
// 69.839 us; speedup vs baseline: 1.0288x; 1.0288x over previous
//
#include <hip/hip_runtime.h>
#include <math.h>

#define BLOCK 256
#define IPB 4   // i's per block

#define PI_F      3.14159265358979323846f
#define TAU_F     6.2831853071795864769f
#define INV_TAU_F 0.15915494309189533577f
// cutoff: dist <= phi^2  <=>  r2 <= phi^4
#define PHI4_F    6.854101966249685f

extern "C" __device__ float __builtin_amdgcn_rsqf(float);

// Per-point precompute: A[i] = {x, y, ell, theta}, x = e^ell*cos(theta), y = e^ell*sin(theta)
__global__ void precompute_kernel(const float* __restrict__ ell,
                                  const float* __restrict__ theta,
                                  float4* __restrict__ A, int n) {
    int i = blockIdx.x * blockDim.x + threadIdx.x;
    if (i < n) {
        float e = ell[i];
        float th = theta[i];
        float lam = expf(e);
        float sn, cs;
        sincosf(th, &sn, &cs);
        A[i] = make_float4(lam * cs, lam * sn, e, th);
    }
}

// Block b owns rows i0..i0+3. Thread t strides j = t, t+256, ... (coalesced
// float4 loads, each amortized over IPB pair computations). Register
// accumulators -> wave butterfly reduce -> LDS cross-wave -> direct store.
// No atomics, no output pre-zeroing needed.
__global__ __launch_bounds__(BLOCK) void repulse_kernel(
        const float4* __restrict__ A,
        const float* __restrict__ s,
        const unsigned char* __restrict__ frozen,
        float* __restrict__ out, int n) {
    const int t  = threadIdx.x;
    const int i0 = blockIdx.x * IPB;

    float xi[IPB], yi[IPB], eli[IPB], api[IPB];
    int   iv[IPB];
#pragma unroll
    for (int v = 0; v < IPB; ++v) {
        int i = i0 + v;
        iv[v] = i;
        float4 a = A[i];
        xi[v] = a.x; yi[v] = a.y; eli[v] = a.z;
        api[v] = PI_F - a.w;          // t_j + (pi - theta_i)
    }

    float Fe[IPB], Ft[IPB];
#pragma unroll
    for (int v = 0; v < IPB; ++v) { Fe[v] = 0.0f; Ft[v] = 0.0f; }

#pragma unroll 4
    for (int j = t; j < n; j += BLOCK) {
        float4 b = A[j];
        float sj = s[j];
#pragma unroll
        for (int v = 0; v < IPB; ++v) {
            float dx = b.x - xi[v];
            float dy = b.y - yi[v];
            float r2 = fmaf(dx, dx, dy * dy);
            float rinv = __builtin_amdgcn_rsqf(fmaxf(r2, 1e-30f));
            bool ok = (r2 <= PHI4_F) && (j != iv[v]);
            float f = ok ? sj * rinv : 0.0f;      // s_j / dist (s_i folded in epilogue)
            float tt = b.w + api[v];              // theta_j - theta_i + pi
            float dth = fmaf(-floorf(tt * INV_TAU_F), TAU_F, tt) - PI_F;
            Fe[v] = fmaf(f, b.z - eli[v], Fe[v]);
            Ft[v] = fmaf(f, dth, Ft[v]);
        }
    }

    // wave-level butterfly reduction (wave = 64 lanes)
#pragma unroll
    for (int v = 0; v < IPB; ++v) {
#pragma unroll
        for (int off = 32; off >= 1; off >>= 1) {
            Fe[v] += __shfl_xor(Fe[v], off, 64);
            Ft[v] += __shfl_xor(Ft[v], off, 64);
        }
    }

    __shared__ float red[(BLOCK / 64) * IPB * 2];   // [wave][v][e/t]
    const int wave = t >> 6;
    const int lane = t & 63;
    if (lane == 0) {
#pragma unroll
        for (int v = 0; v < IPB; ++v) {
            red[wave * IPB * 2 + v * 2 + 0] = Fe[v];
            red[wave * IPB * 2 + v * 2 + 1] = Ft[v];
        }
    }
    __syncthreads();

    // threads 0..IPB*2-1: sum across waves, apply s_i & frozen, store
    if (t < IPB * 2) {
        int v  = t >> 1;
        int c  = t & 1;       // 0 = F_ell, 1 = F_theta
        float sum = 0.0f;
#pragma unroll
        for (int w = 0; w < BLOCK / 64; ++w)
            sum += red[w * IPB * 2 + v * 2 + c];
        int i = i0 + v;
        float val = frozen[i] ? 0.0f : s[i] * sum;
        out[c * n + i] = val;
    }
}

extern "C" void kernel_launch(void* const* d_in, const int* in_sizes, int n_in,
                              void* d_out, int out_size, void* d_ws, size_t ws_size,
                              hipStream_t stream) {
    const float* ell   = (const float*)d_in[0];
    const float* theta = (const float*)d_in[1];
    const float* s     = (const float*)d_in[2];
    const unsigned char* frozen = (const unsigned char*)d_in[3];
    float* out = (float*)d_out;
    int n = in_sizes[0];

    float4* A = (float4*)d_ws;

    int pre_blocks = (n + BLOCK - 1) / BLOCK;
    precompute_kernel<<<pre_blocks, BLOCK, 0, stream>>>(ell, theta, A, n);

    int grid = (n + IPB - 1) / IPB;   // every out element written exactly once
    repulse_kernel<<<grid, BLOCK, 0, stream>>>(A, s, frozen, out, n);
}

// Round 3
// 68.822 us; speedup vs baseline: 1.0440x; 1.0148x over previous
//
#include <hip/hip_runtime.h>
#include <math.h>

#define BLOCK 256
#define IPB 4   // i's per block

#define PI_F      3.14159265358979323846f
#define TAU_F     6.2831853071795864769f
#define INV_TAU_F 0.15915494309189533577f
// cutoff: dist <= phi^2  <=>  r2 <= phi^4
#define PHI4_F    6.854101966249685f

extern "C" __device__ float __builtin_amdgcn_rsqf(float);

// Single fused kernel. Block b owns rows i0..i0+3 (i-data computed once from
// uniform scalar loads). Thread t strides j = t, t+256, ... over all points,
// recomputing x_j,y_j on the fly (__expf/__sincosf are single-instruction
// class; cheaper than a separate precompute dispatch + d_ws round-trip).
// Self-pair masked via r2 > 0 (exact-zero only on the diagonal for random
// inputs). Register accumulators -> wave butterfly -> LDS cross-wave ->
// direct stores (every out element written exactly once; no atomics, no
// pre-zeroing, no workspace).
__global__ __launch_bounds__(BLOCK) void repulse_fused(
        const float* __restrict__ ell,
        const float* __restrict__ theta,
        const float* __restrict__ s,
        const unsigned char* __restrict__ frozen,
        float* __restrict__ out, int n) {
    const int t  = threadIdx.x;
    const int i0 = blockIdx.x * IPB;

    float xi[IPB], yi[IPB], eli[IPB], api[IPB];
#pragma unroll
    for (int v = 0; v < IPB; ++v) {
        int i = i0 + v;                 // uniform -> s_load
        float e  = ell[i];
        float th = theta[i];
        float lam = __expf(e);
        float sn, cs;
        __sincosf(th, &sn, &cs);
        xi[v] = lam * cs; yi[v] = lam * sn;
        eli[v] = e;
        api[v] = PI_F - th;             // dth arg = theta_j + (pi - theta_i)
    }

    float Fe[IPB], Ft[IPB];
#pragma unroll
    for (int v = 0; v < IPB; ++v) { Fe[v] = 0.0f; Ft[v] = 0.0f; }

#pragma unroll 4
    for (int j = t; j < n; j += BLOCK) {
        float e  = ell[j];
        float th = theta[j];
        float sj = s[j];
        float lam = __expf(e);
        float sn, cs;
        __sincosf(th, &sn, &cs);
        float bx = lam * cs, by = lam * sn;
#pragma unroll
        for (int v = 0; v < IPB; ++v) {
            float dx = bx - xi[v];
            float dy = by - yi[v];
            float r2 = fmaf(dx, dx, dy * dy);
            float rinv = __builtin_amdgcn_rsqf(r2);     // rsq(0)=inf, masked below
            bool ok = (r2 <= PHI4_F) && (r2 > 0.0f);    // cutoff + diagonal
            float f = ok ? sj * rinv : 0.0f;            // s_j/dist (s_i in epilogue)
            float tt = th + api[v];                     // theta_j - theta_i + pi
            float dth = fmaf(-floorf(tt * INV_TAU_F), TAU_F, tt) - PI_F;
            Fe[v] = fmaf(f, e - eli[v], Fe[v]);
            Ft[v] = fmaf(f, dth, Ft[v]);
        }
    }

    // wave-level butterfly reduction (wave = 64 lanes)
#pragma unroll
    for (int v = 0; v < IPB; ++v) {
#pragma unroll
        for (int off = 32; off >= 1; off >>= 1) {
            Fe[v] += __shfl_xor(Fe[v], off, 64);
            Ft[v] += __shfl_xor(Ft[v], off, 64);
        }
    }

    __shared__ float red[(BLOCK / 64) * IPB * 2];   // [wave][v][e/t]
    const int wave = t >> 6;
    const int lane = t & 63;
    if (lane == 0) {
#pragma unroll
        for (int v = 0; v < IPB; ++v) {
            red[wave * IPB * 2 + v * 2 + 0] = Fe[v];
            red[wave * IPB * 2 + v * 2 + 1] = Ft[v];
        }
    }
    __syncthreads();

    // threads 0..IPB*2-1: sum across waves, apply s_i & frozen, store
    if (t < IPB * 2) {
        int v = t >> 1;
        int c = t & 1;        // 0 = F_ell, 1 = F_theta
        float sum = 0.0f;
#pragma unroll
        for (int w = 0; w < BLOCK / 64; ++w)
            sum += red[w * IPB * 2 + v * 2 + c];
        int i = i0 + v;
        float val = frozen[i] ? 0.0f : s[i] * sum;
        out[c * n + i] = val;
    }
}

extern "C" void kernel_launch(void* const* d_in, const int* in_sizes, int n_in,
                              void* d_out, int out_size, void* d_ws, size_t ws_size,
                              hipStream_t stream) {
    const float* ell   = (const float*)d_in[0];
    const float* theta = (const float*)d_in[1];
    const float* s     = (const float*)d_in[2];
    const unsigned char* frozen = (const unsigned char*)d_in[3];
    float* out = (float*)d_out;
    int n = in_sizes[0];

    int grid = (n + IPB - 1) / IPB;   // 1024 blocks; every out element written once
    repulse_fused<<<grid, BLOCK, 0, stream>>>(ell, theta, s, frozen, out, n);
}